// Round 1
// baseline (319.758 us; speedup 1.0000x reference)
//
#include <hip/hip_runtime.h>
#include <hip/hip_bf16.h>

#define S_LEN 2048
#define D_DIM 1024
#define NBATCH 4

#define BM 128
#define BN 128
#define BK 32
#define STR 40   // LDS row stride in shorts (80B: 16B-aligned rows, conflict-light)

typedef __attribute__((ext_vector_type(4)))  float f32x4;
typedef __attribute__((ext_vector_type(8)))  short s16x8;   // MFMA bf16 operand (8 bf16)
typedef __attribute__((ext_vector_type(8)))  unsigned short u16x8;
typedef __attribute__((ext_vector_type(4)))  unsigned short u16x4;

__device__ __forceinline__ unsigned short f2b(float f) {
    __hip_bfloat16 h = __float2bfloat16(f);
    return __builtin_bit_cast(unsigned short, h);
}

// ---------------------------------------------------------------------------
// Elementwise fp32 -> bf16 convert (for x). n must be multiple of 1024*4.
__global__ __launch_bounds__(256)
void cvt_kernel(const float* __restrict__ in, unsigned short* __restrict__ out) {
    long i = ((long)blockIdx.x * 256 + threadIdx.x) * 4;
    f32x4 v = *(const f32x4*)(in + i);
    u16x4 o;
    o.x = f2b(v.x); o.y = f2b(v.y); o.z = f2b(v.z); o.w = f2b(v.w);
    *(u16x4*)(out + i) = o;
}

// ---------------------------------------------------------------------------
// W [1024][1024] fp32  ->  WT [1024][1024] bf16 (transposed). z selects matrix.
__global__ __launch_bounds__(256)
void transW_kernel(const float* __restrict__ W0, const float* __restrict__ W1,
                   const float* __restrict__ W2, unsigned short* __restrict__ WT) {
    const float* W = (blockIdx.z == 0) ? W0 : (blockIdx.z == 1) ? W1 : W2;
    unsigned short* O = WT + (long)blockIdx.z * 1024 * 1024;
    __shared__ float t[32][33];
    int tid = threadIdx.x;
    int r  = tid >> 3;        // 0..31
    int c4 = tid & 7;         // 0..7  (float4 col)
    int bi = blockIdx.x, bj = blockIdx.y;
    f32x4 v = *(const f32x4*)&W[(long)(bi * 32 + r) * 1024 + bj * 32 + c4 * 4];
    t[r][c4 * 4 + 0] = v.x; t[r][c4 * 4 + 1] = v.y;
    t[r][c4 * 4 + 2] = v.z; t[r][c4 * 4 + 3] = v.w;
    __syncthreads();
    // WT[n][k], n = bj*32 + r, k = bi*32 + c4*4 + e ; value = W[k][n] = t[k'][n']
    u16x4 o;
    o.x = f2b(t[c4 * 4 + 0][r]); o.y = f2b(t[c4 * 4 + 1][r]);
    o.z = f2b(t[c4 * 4 + 2][r]); o.w = f2b(t[c4 * 4 + 3][r]);
    *(u16x4*)&O[(long)(bj * 32 + r) * 1024 + bi * 32 + c4 * 4] = o;
}

// ---------------------------------------------------------------------------
// Uniform GEMM: C[m][n] = alpha * sum_k A[m][k] * Bt[n][k]
// A: [M][K] bf16 row-major (lda), Bt: [N][K] bf16 row-major (ldb).
// OMODE: 0 = bf16 out, 1 = f32 out.
// CSKIP: causal block skip (scores, requires square 128 tiles): bn > bm -> exit.
// CKLIM: causal K limit (PV): only k < (bm+1)*BM contribute.
template<int OMODE, bool CSKIP, bool CKLIM>
__global__ __launch_bounds__(256)
void gemm_bt(const unsigned short* __restrict__ A, int lda, long aStride,
             const unsigned short* __restrict__ Bt, int ldb, long bStride,
             void* __restrict__ Cv, int ldc, long cStride,
             int K, float alpha) {
    const int bm = blockIdx.x, bn = blockIdx.y, bz = blockIdx.z;
    if (CSKIP && bn > bm) return;
    A  += (long)bz * aStride;
    Bt += (long)bz * bStride;

    const int tid  = threadIdx.x;
    const int lane = tid & 63;
    const int wid  = tid >> 6;
    const int wm   = wid >> 1, wn = wid & 1;   // 2x2 wave grid, 64x64 per wave

    __shared__ unsigned short As[BM * STR];
    __shared__ unsigned short Bs[BN * STR];

    f32x4 acc[4][4] = {};

    const int kend = CKLIM ? (bm + 1) * BM : K;

    // staging map: thread -> (row 0..127, 16-elem half)
    const int srow  = tid >> 1;
    const int shalf = tid & 1;
    const unsigned short* ag = A  + (long)(bm * BM + srow) * lda + shalf * 16;
    const unsigned short* bg = Bt + (long)(bn * BN + srow) * ldb + shalf * 16;

    // fragment map
    const int fr = lane & 15;   // A row / B col within 16
    const int fg = lane >> 4;   // k-slot group (any consistent bijection is valid)

    for (int k0 = 0; k0 < kend; k0 += BK) {
        u16x8 av0 = *(const u16x8*)(ag + k0);
        u16x8 av1 = *(const u16x8*)(ag + k0 + 8);
        u16x8 bv0 = *(const u16x8*)(bg + k0);
        u16x8 bv1 = *(const u16x8*)(bg + k0 + 8);
        __syncthreads();
        *(u16x8*)&As[srow * STR + shalf * 16]     = av0;
        *(u16x8*)&As[srow * STR + shalf * 16 + 8] = av1;
        *(u16x8*)&Bs[srow * STR + shalf * 16]     = bv0;
        *(u16x8*)&Bs[srow * STR + shalf * 16 + 8] = bv1;
        __syncthreads();

        s16x8 af[4], bf[4];
        #pragma unroll
        for (int i = 0; i < 4; i++) {
            const int arow = wm * 64 + i * 16 + fr;
            af[i] = *(const s16x8*)&As[arow * STR + fg * 8];
            const int bcol = wn * 64 + i * 16 + fr;
            bf[i] = *(const s16x8*)&Bs[bcol * STR + fg * 8];
        }
        #pragma unroll
        for (int i = 0; i < 4; i++)
            #pragma unroll
            for (int j = 0; j < 4; j++)
                acc[i][j] = __builtin_amdgcn_mfma_f32_16x16x32_bf16(af[i], bf[j], acc[i][j], 0, 0, 0);
    }

    // epilogue: C/D layout: col = lane&15, row = (lane>>4)*4 + reg
    const int crow0 = bm * BM + wm * 64;
    const int ccol0 = bn * BN + wn * 64;
    const int cr = (lane >> 4) * 4;
    const int cc = lane & 15;
    if (OMODE == 0) {
        unsigned short* C = (unsigned short*)Cv + (long)bz * cStride;
        #pragma unroll
        for (int i = 0; i < 4; i++)
            #pragma unroll
            for (int r = 0; r < 4; r++) {
                const long row = crow0 + i * 16 + cr + r;
                #pragma unroll
                for (int j = 0; j < 4; j++)
                    C[row * ldc + ccol0 + j * 16 + cc] = f2b(acc[i][j][r] * alpha);
            }
    } else {
        float* C = (float*)Cv + (long)bz * cStride;
        #pragma unroll
        for (int i = 0; i < 4; i++)
            #pragma unroll
            for (int r = 0; r < 4; r++) {
                const long row = crow0 + i * 16 + cr + r;
                #pragma unroll
                for (int j = 0; j < 4; j++)
                    C[row * ldc + ccol0 + j * 16 + cc] = acc[i][j][r] * alpha;
            }
    }
}

// ---------------------------------------------------------------------------
// Causal row softmax, in-place fp32 scores row -> bf16 P row (zero-filled past i).
__global__ __launch_bounds__(256)
void softmax_rows(float* __restrict__ scores) {
    const int i = blockIdx.x;              // row within batch
    const int z = blockIdx.y;              // batch within chunk
    float* row = scores + ((long)z * S_LEN + i) * S_LEN;
    const int c = i + 1;                   // valid entries
    const int tid  = threadIdx.x;
    const int lane = tid & 63;
    const int wid  = tid >> 6;

    f32x4 v0 = ((const f32x4*)row)[tid];
    f32x4 v1 = ((const f32x4*)row)[tid + 256];
    const int j0 = tid * 4, j1 = (tid + 256) * 4;

    float m = -3.4e38f;
    #pragma unroll
    for (int e = 0; e < 4; e++) {
        if (j0 + e < c) m = fmaxf(m, v0[e]);
        if (j1 + e < c) m = fmaxf(m, v1[e]);
    }
    #pragma unroll
    for (int off = 32; off > 0; off >>= 1) m = fmaxf(m, __shfl_xor(m, off));
    __shared__ float redm[4];
    if (lane == 0) redm[wid] = m;
    __syncthreads();
    m = fmaxf(fmaxf(redm[0], redm[1]), fmaxf(redm[2], redm[3]));

    float e0[4], e1[4];
    float s = 0.f;
    #pragma unroll
    for (int e = 0; e < 4; e++) {
        e0[e] = (j0 + e < c) ? __expf(v0[e] - m) : 0.f;
        e1[e] = (j1 + e < c) ? __expf(v1[e] - m) : 0.f;
        s += e0[e] + e1[e];
    }
    #pragma unroll
    for (int off = 32; off > 0; off >>= 1) s += __shfl_xor(s, off);
    __shared__ float reds[4];
    if (lane == 0) reds[wid] = s;
    __syncthreads();   // also guarantees every thread's loads retired before in-place writes
    s = reds[0] + reds[1] + reds[2] + reds[3];
    const float rinv = 1.f / s;

    unsigned short* P = (unsigned short*)row;   // in-place bf16 (row stride stays 8192 B)
    u16x4 o0, o1;
    o0.x = f2b(e0[0] * rinv); o0.y = f2b(e0[1] * rinv);
    o0.z = f2b(e0[2] * rinv); o0.w = f2b(e0[3] * rinv);
    o1.x = f2b(e1[0] * rinv); o1.y = f2b(e1[1] * rinv);
    o1.z = f2b(e1[2] * rinv); o1.w = f2b(e1[3] * rinv);
    *(u16x4*)&P[j0] = o0;
    *(u16x4*)&P[j1] = o1;
}

// ---------------------------------------------------------------------------
extern "C" void kernel_launch(void* const* d_in, const int* in_sizes, int n_in,
                              void* d_out, int out_size, void* d_ws, size_t ws_size,
                              hipStream_t stream) {
    const float* x  = (const float*)d_in[0];
    const float* Wq = (const float*)d_in[1];
    const float* Wk = (const float*)d_in[2];
    const float* Wv = (const float*)d_in[3];
    float* out = (float*)d_out;
    char* ws = (char*)d_ws;
    const size_t MiB = 1ull << 20;

    unsigned short* xb  = (unsigned short*)(ws);              // [8192][1024] bf16, 16 MiB
    unsigned short* WT  = (unsigned short*)(ws + 16 * MiB);   // 3x [1024][1024] bf16, 6 MiB
    unsigned short* Qb  = (unsigned short*)(ws + 22 * MiB);   // [4][2048][1024], 16 MiB
    unsigned short* Kb  = (unsigned short*)(ws + 38 * MiB);   // [4][2048][1024], 16 MiB
    unsigned short* VbT = (unsigned short*)(ws + 54 * MiB);   // [1024][8192] (=V^T per batch cols), 16 MiB
    float* scores       = (float*)(ws + 70 * MiB);            // nb x [2048][2048] fp32

    int nb;   // batches of scores materialized at once (adapts to ws_size)
    if      (ws_size >= (70 + 64) * MiB) nb = 4;
    else if (ws_size >= (70 + 32) * MiB) nb = 2;
    else                                 nb = 1;

    // 1) converts
    cvt_kernel<<<8192, 256, 0, stream>>>(x, xb);                       // 8.4M elems
    transW_kernel<<<dim3(32, 32, 3), 256, 0, stream>>>(Wq, Wk, Wv, WT);

    // 2) projections: Q,K = x*W  (z in {0,1} picks Wq/Wk and Qb/Kb)
    gemm_bt<0, false, false><<<dim3(64, 8, 2), 256, 0, stream>>>(
        xb, 1024, 0L, WT, 1024, (long)1024 * 1024,
        Qb, 1024, (long)8192 * 1024, 1024, 1.0f);
    // V^T = Wv^T * x^T  -> [1024][8192]
    gemm_bt<0, false, false><<<dim3(8, 64, 1), 256, 0, stream>>>(
        WT + (long)2 * 1024 * 1024, 1024, 0L, xb, 1024, 0L,
        VbT, 8192, 0L, 1024, 1.0f);

    // 3) attention, chunked over batches
    const float alpha = 0.03125f;   // 1/sqrt(1024)
    for (int b0 = 0; b0 < NBATCH; b0 += nb) {
        const int nz = (NBATCH - b0 < nb) ? (NBATCH - b0) : nb;
        // scores = Q K^T * alpha  (lower-triangular 128-blocks only)
        gemm_bt<1, true, false><<<dim3(16, 16, nz), 256, 0, stream>>>(
            Qb + (long)b0 * S_LEN * D_DIM, 1024, (long)S_LEN * D_DIM,
            Kb + (long)b0 * S_LEN * D_DIM, 1024, (long)S_LEN * D_DIM,
            scores, S_LEN, (long)S_LEN * S_LEN, 1024, alpha);
        // softmax rows (in-place bf16 P)
        softmax_rows<<<dim3(S_LEN, nz), 256, 0, stream>>>(scores);
        // O = P V  (K limited per block row; P rows live at bf16 stride 4096)
        gemm_bt<1, false, true><<<dim3(16, 8, nz), 256, 0, stream>>>(
            (const unsigned short*)scores, 2 * S_LEN, 2L * S_LEN * S_LEN,
            VbT + (long)b0 * S_LEN, 8192, (long)S_LEN,
            out + (long)b0 * S_LEN * D_DIM, 1024, (long)S_LEN * D_DIM,
            S_LEN, 1.0f);
    }
}

// Round 2
// 310.374 us; speedup vs baseline: 1.0302x; 1.0302x over previous
//
#include <hip/hip_runtime.h>
#include <hip/hip_bf16.h>

#define S_LEN 2048
#define D_DIM 1024
#define NBATCH 4

#define BM 128
#define BN 128
#define BK 32

typedef __attribute__((ext_vector_type(4)))  float f32x4;
typedef __attribute__((ext_vector_type(8)))  short s16x8;   // MFMA bf16 operand (8 bf16)
typedef __attribute__((ext_vector_type(8)))  unsigned short u16x8;
typedef __attribute__((ext_vector_type(4)))  unsigned short u16x4;

__device__ __forceinline__ unsigned short f2b(float f) {
    __hip_bfloat16 h = __float2bfloat16(f);
    return __builtin_bit_cast(unsigned short, h);
}

// Direct global->LDS DMA, 16 bytes per lane. LDS dest must be linear in lane order.
__device__ __forceinline__ void load_lds16(const unsigned short* g, unsigned short* l) {
    __builtin_amdgcn_global_load_lds(
        (const __attribute__((address_space(1))) void*)(g),
        (__attribute__((address_space(3))) void*)(l), 16, 0, 0);
}

// ---------------------------------------------------------------------------
// Elementwise fp32 -> bf16 convert (for x). n must be multiple of 1024*4.
__global__ __launch_bounds__(256)
void cvt_kernel(const float* __restrict__ in, unsigned short* __restrict__ out) {
    long i = ((long)blockIdx.x * 256 + threadIdx.x) * 4;
    f32x4 v = *(const f32x4*)(in + i);
    u16x4 o;
    o.x = f2b(v.x); o.y = f2b(v.y); o.z = f2b(v.z); o.w = f2b(v.w);
    *(u16x4*)(out + i) = o;
}

// ---------------------------------------------------------------------------
// W [1024][1024] fp32  ->  WT [1024][1024] bf16 (transposed). z selects matrix.
__global__ __launch_bounds__(256)
void transW_kernel(const float* __restrict__ W0, const float* __restrict__ W1,
                   const float* __restrict__ W2, unsigned short* __restrict__ WT) {
    const float* W = (blockIdx.z == 0) ? W0 : (blockIdx.z == 1) ? W1 : W2;
    unsigned short* O = WT + (long)blockIdx.z * 1024 * 1024;
    __shared__ float t[32][33];
    int tid = threadIdx.x;
    int r  = tid >> 3;        // 0..31
    int c4 = tid & 7;         // 0..7  (float4 col)
    int bi = blockIdx.x, bj = blockIdx.y;
    f32x4 v = *(const f32x4*)&W[(long)(bi * 32 + r) * 1024 + bj * 32 + c4 * 4];
    t[r][c4 * 4 + 0] = v.x; t[r][c4 * 4 + 1] = v.y;
    t[r][c4 * 4 + 2] = v.z; t[r][c4 * 4 + 3] = v.w;
    __syncthreads();
    u16x4 o;
    o.x = f2b(t[c4 * 4 + 0][r]); o.y = f2b(t[c4 * 4 + 1][r]);
    o.z = f2b(t[c4 * 4 + 2][r]); o.w = f2b(t[c4 * 4 + 3][r]);
    *(u16x4*)&O[(long)(bj * 32 + r) * 1024 + bi * 32 + c4 * 4] = o;
}

// ---------------------------------------------------------------------------
// Uniform GEMM (m97 structure): C[m][n] = alpha * sum_k A[m][k] * Bt[n][k]
// A: [M][K] bf16 row-major (lda), Bt: [N][K] bf16 row-major (ldb).
// Staging via global_load_lds width=16 into LINEAR [128][32] LDS tiles.
// OMODE: 0 = bf16 out, 1 = f32 out.
// CSKIP: causal block skip (scores): bn > bm -> exit.
// CKLIM: causal K limit (PV): only k < (bm+1)*BM contribute.
template<int OMODE, bool CSKIP, bool CKLIM>
__global__ __launch_bounds__(256)
void gemm_bt(const unsigned short* __restrict__ A, int lda, long aStride,
             const unsigned short* __restrict__ Bt, int ldb, long bStride,
             void* __restrict__ Cv, int ldc, long cStride,
             int K, float alpha) {
    const int bm = blockIdx.x, bn = blockIdx.y, bz = blockIdx.z;
    if (CSKIP && bn > bm) return;
    A  += (long)bz * aStride;
    Bt += (long)bz * bStride;

    const int tid  = threadIdx.x;
    const int lane = tid & 63;
    const int wid  = tid >> 6;
    const int wm   = wid >> 1, wn = wid & 1;   // 2x2 wave grid, 64x64 per wave

    __shared__ __align__(16) unsigned short As[BM * BK];   // 8 KiB, linear
    __shared__ __align__(16) unsigned short Bs[BN * BK];   // 8 KiB, linear

    f32x4 acc[4][4] = {};
    const int kend = CKLIM ? (bm + 1) * BM : K;

    // staging map: wave wid owns chunks {wid*2, wid*2+1} of each tile.
    // chunk c covers rows [c*16, c*16+16); lane l -> row c*16 + l/4, col (l&3)*8.
    const int c0   = wid * 2;
    const int srow = c0 * 16 + (lane >> 2);
    const int scol = (lane & 3) * 8;
    const unsigned short* ag = A  + (long)(bm * BM + srow) * lda + scol;
    const unsigned short* bg = Bt + (long)(bn * BN + srow) * ldb + scol;
    unsigned short* la0 = &As[c0 * 512 + lane * 8];
    unsigned short* lb0 = &Bs[c0 * 512 + lane * 8];

    // fragment map
    const int fr = lane & 15;   // A row / B col within 16
    const int fg = lane >> 4;   // k-slot group (same bijection on A and B)

    for (int k0 = 0; k0 < kend; k0 += BK) {
        load_lds16(ag + k0,            la0);
        load_lds16(ag + 16 * lda + k0, la0 + 512);
        load_lds16(bg + k0,            lb0);
        load_lds16(bg + 16 * ldb + k0, lb0 + 512);
        __syncthreads();   // vmcnt(0)-drained by compiler: staged data visible

        s16x8 af[4], bf[4];
        #pragma unroll
        for (int i = 0; i < 4; i++) {
            af[i] = *(const s16x8*)&As[(wm * 64 + i * 16 + fr) * BK + fg * 8];
            bf[i] = *(const s16x8*)&Bs[(wn * 64 + i * 16 + fr) * BK + fg * 8];
        }
        #pragma unroll
        for (int i = 0; i < 4; i++)
            #pragma unroll
            for (int j = 0; j < 4; j++)
                acc[i][j] = __builtin_amdgcn_mfma_f32_16x16x32_bf16(af[i], bf[j], acc[i][j], 0, 0, 0);
        __syncthreads();   // all reads done before next iter's staging overwrites
    }

    // epilogue: C/D layout: col = lane&15, row = (lane>>4)*4 + reg
    const int crow0 = bm * BM + wm * 64;
    const int ccol0 = bn * BN + wn * 64;
    const int cr = (lane >> 4) * 4;
    const int cc = lane & 15;
    if (OMODE == 0) {
        unsigned short* C = (unsigned short*)Cv + (long)bz * cStride;
        #pragma unroll
        for (int i = 0; i < 4; i++)
            #pragma unroll
            for (int r = 0; r < 4; r++) {
                const long row = crow0 + i * 16 + cr + r;
                #pragma unroll
                for (int j = 0; j < 4; j++)
                    C[row * ldc + ccol0 + j * 16 + cc] = f2b(acc[i][j][r] * alpha);
            }
    } else {
        float* C = (float*)Cv + (long)bz * cStride;
        #pragma unroll
        for (int i = 0; i < 4; i++)
            #pragma unroll
            for (int r = 0; r < 4; r++) {
                const long row = crow0 + i * 16 + cr + r;
                #pragma unroll
                for (int j = 0; j < 4; j++)
                    C[row * ldc + ccol0 + j * 16 + cc] = acc[i][j][r] * alpha;
            }
    }
}

// ---------------------------------------------------------------------------
// Causal row softmax, in-place fp32 scores row -> bf16 P row (zero-filled past i).
__global__ __launch_bounds__(256)
void softmax_rows(float* __restrict__ scores) {
    const int i = blockIdx.x;              // row within batch
    const int z = blockIdx.y;              // batch within chunk
    float* row = scores + ((long)z * S_LEN + i) * S_LEN;
    const int c = i + 1;                   // valid entries
    const int tid  = threadIdx.x;
    const int lane = tid & 63;
    const int wid  = tid >> 6;

    f32x4 v0 = ((const f32x4*)row)[tid];
    f32x4 v1 = ((const f32x4*)row)[tid + 256];
    const int j0 = tid * 4, j1 = (tid + 256) * 4;

    float m = -3.4e38f;
    #pragma unroll
    for (int e = 0; e < 4; e++) {
        if (j0 + e < c) m = fmaxf(m, v0[e]);
        if (j1 + e < c) m = fmaxf(m, v1[e]);
    }
    #pragma unroll
    for (int off = 32; off > 0; off >>= 1) m = fmaxf(m, __shfl_xor(m, off));
    __shared__ float redm[4];
    if (lane == 0) redm[wid] = m;
    __syncthreads();
    m = fmaxf(fmaxf(redm[0], redm[1]), fmaxf(redm[2], redm[3]));

    float e0[4], e1[4];
    float s = 0.f;
    #pragma unroll
    for (int e = 0; e < 4; e++) {
        e0[e] = (j0 + e < c) ? __expf(v0[e] - m) : 0.f;
        e1[e] = (j1 + e < c) ? __expf(v1[e] - m) : 0.f;
        s += e0[e] + e1[e];
    }
    #pragma unroll
    for (int off = 32; off > 0; off >>= 1) s += __shfl_xor(s, off);
    __shared__ float reds[4];
    if (lane == 0) reds[wid] = s;
    __syncthreads();   // also guarantees every thread's loads retired before in-place writes
    s = reds[0] + reds[1] + reds[2] + reds[3];
    const float rinv = 1.f / s;

    unsigned short* P = (unsigned short*)row;   // in-place bf16 (row stride stays 8192 B)
    u16x4 o0, o1;
    o0.x = f2b(e0[0] * rinv); o0.y = f2b(e0[1] * rinv);
    o0.z = f2b(e0[2] * rinv); o0.w = f2b(e0[3] * rinv);
    o1.x = f2b(e1[0] * rinv); o1.y = f2b(e1[1] * rinv);
    o1.z = f2b(e1[2] * rinv); o1.w = f2b(e1[3] * rinv);
    *(u16x4*)&P[j0] = o0;
    *(u16x4*)&P[j1] = o1;
}

// ---------------------------------------------------------------------------
extern "C" void kernel_launch(void* const* d_in, const int* in_sizes, int n_in,
                              void* d_out, int out_size, void* d_ws, size_t ws_size,
                              hipStream_t stream) {
    const float* x  = (const float*)d_in[0];
    const float* Wq = (const float*)d_in[1];
    const float* Wk = (const float*)d_in[2];
    const float* Wv = (const float*)d_in[3];
    float* out = (float*)d_out;
    char* ws = (char*)d_ws;
    const size_t MiB = 1ull << 20;

    unsigned short* xb  = (unsigned short*)(ws);              // [8192][1024] bf16, 16 MiB
    unsigned short* WT  = (unsigned short*)(ws + 16 * MiB);   // 3x [1024][1024] bf16, 6 MiB
    unsigned short* Qb  = (unsigned short*)(ws + 22 * MiB);   // [4][2048][1024], 16 MiB
    unsigned short* Kb  = (unsigned short*)(ws + 38 * MiB);   // [4][2048][1024], 16 MiB
    unsigned short* VbT = (unsigned short*)(ws + 54 * MiB);   // [1024][8192] (=V^T per batch cols), 16 MiB
    float* scores       = (float*)(ws + 70 * MiB);            // nb x [2048][2048] fp32

    int nb;   // batches of scores materialized at once (adapts to ws_size)
    if      (ws_size >= (70 + 64) * MiB) nb = 4;
    else if (ws_size >= (70 + 32) * MiB) nb = 2;
    else                                 nb = 1;

    // 1) converts
    cvt_kernel<<<8192, 256, 0, stream>>>(x, xb);
    transW_kernel<<<dim3(32, 32, 3), 256, 0, stream>>>(Wq, Wk, Wv, WT);

    // 2) projections: Q,K = x*W  (z in {0,1} picks Wq/Wk and Qb/Kb)
    gemm_bt<0, false, false><<<dim3(64, 8, 2), 256, 0, stream>>>(
        xb, 1024, 0L, WT, 1024, (long)1024 * 1024,
        Qb, 1024, (long)8192 * 1024, 1024, 1.0f);
    // V^T = Wv^T * x^T  -> [1024][8192]
    gemm_bt<0, false, false><<<dim3(8, 64, 1), 256, 0, stream>>>(
        WT + (long)2 * 1024 * 1024, 1024, 0L, xb, 1024, 0L,
        VbT, 8192, 0L, 1024, 1.0f);

    // 3) attention, chunked over batches
    const float alpha = 0.03125f;   // 1/sqrt(1024)
    for (int b0 = 0; b0 < NBATCH; b0 += nb) {
        const int nz = (NBATCH - b0 < nb) ? (NBATCH - b0) : nb;
        // scores = Q K^T * alpha  (lower-triangular 128-blocks only)
        gemm_bt<1, true, false><<<dim3(16, 16, nz), 256, 0, stream>>>(
            Qb + (long)b0 * S_LEN * D_DIM, 1024, (long)S_LEN * D_DIM,
            Kb + (long)b0 * S_LEN * D_DIM, 1024, (long)S_LEN * D_DIM,
            scores, S_LEN, (long)S_LEN * S_LEN, 1024, alpha);
        // softmax rows (in-place bf16 P)
        softmax_rows<<<dim3(S_LEN, nz), 256, 0, stream>>>(scores);
        // O = P V  (K limited per block row; P rows live at bf16 stride 4096)
        gemm_bt<1, false, true><<<dim3(16, 8, nz), 256, 0, stream>>>(
            (const unsigned short*)scores, 2 * S_LEN, 2L * S_LEN * S_LEN,
            VbT + (long)b0 * S_LEN, 8192, (long)S_LEN,
            out + (long)b0 * S_LEN * D_DIM, 1024, (long)S_LEN * D_DIM,
            S_LEN, 1.0f);
    }
}

// Round 4
// 270.154 us; speedup vs baseline: 1.1836x; 1.1489x over previous
//
#include <hip/hip_runtime.h>
#include <hip/hip_bf16.h>

#define S_LEN 2048
#define D_DIM 1024
#define NBATCH 4

#define BM 128
#define BN 128
#define BK 32
#define TILE (BM * BK)   // 4096 shorts = 8 KiB per buffer

typedef __attribute__((ext_vector_type(4)))  float f32x4;
typedef __attribute__((ext_vector_type(8)))  short s16x8;   // MFMA bf16 operand (8 bf16)
typedef __attribute__((ext_vector_type(8)))  unsigned short u16x8;
typedef __attribute__((ext_vector_type(4)))  unsigned short u16x4;

__device__ __forceinline__ unsigned short f2b(float f) {
    __hip_bfloat16 h = __float2bfloat16(f);
    return __builtin_bit_cast(unsigned short, h);
}

// Direct global->LDS DMA, 16 bytes per lane. LDS dest must be linear in lane order.
__device__ __forceinline__ void load_lds16(const unsigned short* g, unsigned short* l) {
    __builtin_amdgcn_global_load_lds(
        (const __attribute__((address_space(1))) void*)(g),
        (__attribute__((address_space(3))) void*)(l), 16, 0, 0);
}

// ---------------------------------------------------------------------------
// Elementwise fp32 -> bf16 convert (for x). n must be multiple of 1024*4.
__global__ __launch_bounds__(256)
void cvt_kernel(const float* __restrict__ in, unsigned short* __restrict__ out) {
    long i = ((long)blockIdx.x * 256 + threadIdx.x) * 4;
    f32x4 v = *(const f32x4*)(in + i);
    u16x4 o;
    o.x = f2b(v.x); o.y = f2b(v.y); o.z = f2b(v.z); o.w = f2b(v.w);
    *(u16x4*)(out + i) = o;
}

// ---------------------------------------------------------------------------
// W [1024][1024] fp32  ->  WT [1024][1024] bf16 (transposed). z selects matrix.
__global__ __launch_bounds__(256)
void transW_kernel(const float* __restrict__ W0, const float* __restrict__ W1,
                   const float* __restrict__ W2, unsigned short* __restrict__ WT) {
    const float* W = (blockIdx.z == 0) ? W0 : (blockIdx.z == 1) ? W1 : W2;
    unsigned short* O = WT + (long)blockIdx.z * 1024 * 1024;
    __shared__ float t[32][33];
    int tid = threadIdx.x;
    int r  = tid >> 3;        // 0..31
    int c4 = tid & 7;         // 0..7  (float4 col)
    int bi = blockIdx.x, bj = blockIdx.y;
    f32x4 v = *(const f32x4*)&W[(long)(bi * 32 + r) * 1024 + bj * 32 + c4 * 4];
    t[r][c4 * 4 + 0] = v.x; t[r][c4 * 4 + 1] = v.y;
    t[r][c4 * 4 + 2] = v.z; t[r][c4 * 4 + 3] = v.w;
    __syncthreads();
    u16x4 o;
    o.x = f2b(t[c4 * 4 + 0][r]); o.y = f2b(t[c4 * 4 + 1][r]);
    o.z = f2b(t[c4 * 4 + 2][r]); o.w = f2b(t[c4 * 4 + 3][r]);
    *(u16x4*)&O[(long)(bj * 32 + r) * 1024 + bi * 32 + c4 * 4] = o;
}

// ---------------------------------------------------------------------------
// Uniform GEMM, double-buffered pipeline: C[m][n] = alpha * sum_k A[m][k]*Bt[n][k]
// A: [M][K] bf16 row-major (lda), Bt: [N][K] bf16 row-major (ldb).
// Staging via global_load_lds width=16 into LINEAR [128][32] LDS tiles, 2 buffers.
// Pipeline: prefetch tile t+1 at top of iter t; one __syncthreads per iter
// (its implicit vmcnt(0)+lgkmcnt(0) drain makes the stage visible AND orders
// this iter's ds_reads before next iter's overwrite).
// OMODE: 0 = bf16 out, 1 = f32 out.
// CSKIP: causal block skip (scores): bn > bm -> exit.
// CKLIM: causal K limit (PV): only k < (bm+1)*BM contribute.
template<int OMODE, bool CSKIP, bool CKLIM>
__global__ __launch_bounds__(256)
void gemm_bt(const unsigned short* __restrict__ A, int lda, long aStride,
             const unsigned short* __restrict__ Bt, int ldb, long bStride,
             void* __restrict__ Cv, int ldc, long cStride,
             int K, float alpha) {
    const int bm = blockIdx.x, bn = blockIdx.y, bz = blockIdx.z;
    if (CSKIP && bn > bm) return;
    A  += (long)bz * aStride;
    Bt += (long)bz * bStride;

    const int tid  = threadIdx.x;
    const int lane = tid & 63;
    const int wid  = tid >> 6;
    const int wm   = wid >> 1, wn = wid & 1;   // 2x2 wave grid, 64x64 per wave

    __shared__ __align__(16) unsigned short As[2][TILE];   // 2 x 8 KiB
    __shared__ __align__(16) unsigned short Bs[2][TILE];   // 2 x 8 KiB

    f32x4 acc[4][4] = {};
    const int kend = CKLIM ? (bm + 1) * BM : K;
    const int nt   = kend / BK;

    // staging map: wave wid owns chunks {wid*2, wid*2+1} (16 rows each).
    // chunk c, lane l -> row c*16 + l/4, col (l&3)*8; LDS linear in lane order.
    const int c0   = wid * 2;
    const int srow = c0 * 16 + (lane >> 2);
    const int scol = (lane & 3) * 8;
    const unsigned short* ag = A  + (long)(bm * BM + srow) * lda + scol;
    const unsigned short* bg = Bt + (long)(bn * BN + srow) * ldb + scol;
    const int l0 = c0 * 512 + lane * 8;   // linear LDS elem offset of chunk c0

    // fragment map
    const int fr = lane & 15;   // A row / B col within 16
    const int fg = lane >> 4;   // k-slot group (same bijection on A and B)

    // prologue: stage tile 0 into buffer 0
    load_lds16(ag, &As[0][l0]);
    load_lds16(ag + 16 * lda, &As[0][l0 + 512]);
    load_lds16(bg, &Bs[0][l0]);
    load_lds16(bg + 16 * ldb, &Bs[0][l0 + 512]);
    __syncthreads();

    for (int t = 0; t < nt; ++t) {
        const int cur = t & 1;
        if (t + 1 < nt) {   // prefetch tile t+1 into the other buffer
            const int k0 = (t + 1) * BK;
            load_lds16(ag + k0,            &As[cur ^ 1][l0]);
            load_lds16(ag + 16 * lda + k0, &As[cur ^ 1][l0 + 512]);
            load_lds16(bg + k0,            &Bs[cur ^ 1][l0]);
            load_lds16(bg + 16 * ldb + k0, &Bs[cur ^ 1][l0 + 512]);
        }

        s16x8 af[4], bf[4];
        #pragma unroll
        for (int i = 0; i < 4; i++) {
            af[i] = *(const s16x8*)&As[cur][(wm * 64 + i * 16 + fr) * BK + fg * 8];
            bf[i] = *(const s16x8*)&Bs[cur][(wn * 64 + i * 16 + fr) * BK + fg * 8];
        }
        #pragma unroll
        for (int i = 0; i < 4; i++)
            #pragma unroll
            for (int j = 0; j < 4; j++)
                acc[i][j] = __builtin_amdgcn_mfma_f32_16x16x32_bf16(af[i], bf[j], acc[i][j], 0, 0, 0);

        __syncthreads();   // drain stage (vmcnt0) + order reads before overwrite
    }

    // epilogue: C/D layout: col = lane&15, row = (lane>>4)*4 + reg
    const int crow0 = bm * BM + wm * 64;
    const int ccol0 = bn * BN + wn * 64;
    const int cr = (lane >> 4) * 4;
    const int cc = lane & 15;
    if (OMODE == 0) {
        unsigned short* C = (unsigned short*)Cv + (long)bz * cStride;
        #pragma unroll
        for (int i = 0; i < 4; i++)
            #pragma unroll
            for (int r = 0; r < 4; r++) {
                const long row = crow0 + i * 16 + cr + r;
                #pragma unroll
                for (int j = 0; j < 4; j++)
                    C[row * ldc + ccol0 + j * 16 + cc] = f2b(acc[i][j][r] * alpha);
            }
    } else {
        float* C = (float*)Cv + (long)bz * cStride;
        #pragma unroll
        for (int i = 0; i < 4; i++)
            #pragma unroll
            for (int r = 0; r < 4; r++) {
                const long row = crow0 + i * 16 + cr + r;
                #pragma unroll
                for (int j = 0; j < 4; j++)
                    C[row * ldc + ccol0 + j * 16 + cc] = acc[i][j][r] * alpha;
            }
    }
}

// ---------------------------------------------------------------------------
// Causal row softmax, in-place fp32 scores row -> bf16 P row (zero-filled past i).
__global__ __launch_bounds__(256)
void softmax_rows(float* __restrict__ scores) {
    const int i = blockIdx.x;              // row within batch
    const int z = blockIdx.y;              // batch within chunk
    float* row = scores + ((long)z * S_LEN + i) * S_LEN;
    const int c = i + 1;                   // valid entries
    const int tid  = threadIdx.x;
    const int lane = tid & 63;
    const int wid  = tid >> 6;

    f32x4 v0 = ((const f32x4*)row)[tid];
    f32x4 v1 = ((const f32x4*)row)[tid + 256];
    const int j0 = tid * 4, j1 = (tid + 256) * 4;

    float m = -3.4e38f;
    #pragma unroll
    for (int e = 0; e < 4; e++) {
        if (j0 + e < c) m = fmaxf(m, v0[e]);
        if (j1 + e < c) m = fmaxf(m, v1[e]);
    }
    #pragma unroll
    for (int off = 32; off > 0; off >>= 1) m = fmaxf(m, __shfl_xor(m, off));
    __shared__ float redm[4];
    if (lane == 0) redm[wid] = m;
    __syncthreads();
    m = fmaxf(fmaxf(redm[0], redm[1]), fmaxf(redm[2], redm[3]));

    float e0[4], e1[4];
    float s = 0.f;
    #pragma unroll
    for (int e = 0; e < 4; e++) {
        e0[e] = (j0 + e < c) ? __expf(v0[e] - m) : 0.f;
        e1[e] = (j1 + e < c) ? __expf(v1[e] - m) : 0.f;
        s += e0[e] + e1[e];
    }
    #pragma unroll
    for (int off = 32; off > 0; off >>= 1) s += __shfl_xor(s, off);
    __shared__ float reds[4];
    if (lane == 0) reds[wid] = s;
    __syncthreads();   // also guarantees every thread's loads retired before in-place writes
    s = reds[0] + reds[1] + reds[2] + reds[3];
    const float rinv = 1.f / s;

    unsigned short* P = (unsigned short*)row;   // in-place bf16 (row stride stays 8192 B)
    u16x4 o0, o1;
    o0.x = f2b(e0[0] * rinv); o0.y = f2b(e0[1] * rinv);
    o0.z = f2b(e0[2] * rinv); o0.w = f2b(e0[3] * rinv);
    o1.x = f2b(e1[0] * rinv); o1.y = f2b(e1[1] * rinv);
    o1.z = f2b(e1[2] * rinv); o1.w = f2b(e1[3] * rinv);
    *(u16x4*)&P[j0] = o0;
    *(u16x4*)&P[j1] = o1;
}

// ---------------------------------------------------------------------------
extern "C" void kernel_launch(void* const* d_in, const int* in_sizes, int n_in,
                              void* d_out, int out_size, void* d_ws, size_t ws_size,
                              hipStream_t stream) {
    const float* x  = (const float*)d_in[0];
    const float* Wq = (const float*)d_in[1];
    const float* Wk = (const float*)d_in[2];
    const float* Wv = (const float*)d_in[3];
    float* out = (float*)d_out;
    char* ws = (char*)d_ws;
    const size_t MiB = 1ull << 20;

    unsigned short* xb  = (unsigned short*)(ws);              // [8192][1024] bf16, 16 MiB
    unsigned short* WT  = (unsigned short*)(ws + 16 * MiB);   // 3x [1024][1024] bf16, 6 MiB
    unsigned short* Qb  = (unsigned short*)(ws + 22 * MiB);   // [4][2048][1024], 16 MiB
    unsigned short* Kb  = (unsigned short*)(ws + 38 * MiB);   // [4][2048][1024], 16 MiB
    unsigned short* VbT = (unsigned short*)(ws + 54 * MiB);   // [1024][8192] (=V^T per batch cols), 16 MiB
    float* scores       = (float*)(ws + 70 * MiB);            // nb x [2048][2048] fp32

    int nb;   // batches of scores materialized at once (adapts to ws_size)
    if      (ws_size >= (70 + 64) * MiB) nb = 4;
    else if (ws_size >= (70 + 32) * MiB) nb = 2;
    else                                 nb = 1;

    // 1) converts
    cvt_kernel<<<8192, 256, 0, stream>>>(x, xb);
    transW_kernel<<<dim3(32, 32, 3), 256, 0, stream>>>(Wq, Wk, Wv, WT);

    // 2) projections: Q,K = x*W  (z in {0,1} picks Wq/Wk and Qb/Kb)
    gemm_bt<0, false, false><<<dim3(64, 8, 2), 256, 0, stream>>>(
        xb, 1024, 0L, WT, 1024, (long)1024 * 1024,
        Qb, 1024, (long)8192 * 1024, 1024, 1.0f);
    // V^T = Wv^T * x^T  -> [1024][8192]
    gemm_bt<0, false, false><<<dim3(8, 64, 1), 256, 0, stream>>>(
        WT + (long)2 * 1024 * 1024, 1024, 0L, xb, 1024, 0L,
        VbT, 8192, 0L, 1024, 1.0f);

    // 3) attention, chunked over batches
    const float alpha = 0.03125f;   // 1/sqrt(1024)
    for (int b0 = 0; b0 < NBATCH; b0 += nb) {
        const int nz = (NBATCH - b0 < nb) ? (NBATCH - b0) : nb;
        // scores = Q K^T * alpha  (lower-triangular 128-blocks only)
        gemm_bt<1, true, false><<<dim3(16, 16, nz), 256, 0, stream>>>(
            Qb + (long)b0 * S_LEN * D_DIM, 1024, (long)S_LEN * D_DIM,
            Kb + (long)b0 * S_LEN * D_DIM, 1024, (long)S_LEN * D_DIM,
            scores, S_LEN, (long)S_LEN * S_LEN, 1024, alpha);
        // softmax rows (in-place bf16 P)
        softmax_rows<<<dim3(S_LEN, nz), 256, 0, stream>>>(scores);
        // O = P V  (K limited per block row; P rows live at bf16 stride 4096)
        gemm_bt<1, false, true><<<dim3(16, 8, nz), 256, 0, stream>>>(
            (const unsigned short*)scores, 2 * S_LEN, 2L * S_LEN * S_LEN,
            VbT + (long)b0 * S_LEN, 8192, (long)S_LEN,
            out + (long)b0 * S_LEN * D_DIM, 1024, (long)S_LEN * D_DIM,
            S_LEN, 1.0f);
    }
}

// Round 5
// 242.854 us; speedup vs baseline: 1.3167x; 1.1124x over previous
//
#include <hip/hip_runtime.h>
#include <hip/hip_bf16.h>

#define S_LEN 2048
#define D_DIM 1024
#define NBATCH 4

typedef __attribute__((ext_vector_type(4)))  float f32x4;
typedef __attribute__((ext_vector_type(8)))  short s16x8;   // MFMA bf16 operand
typedef __attribute__((ext_vector_type(4)))  unsigned short u16x4;

__device__ __forceinline__ unsigned short f2b(float f) {
    __hip_bfloat16 h = __float2bfloat16(f);
    return __builtin_bit_cast(unsigned short, h);
}

// Direct global->LDS DMA, 16 bytes per lane. LDS dest must be linear in lane order.
__device__ __forceinline__ void load_lds16(const unsigned short* g, unsigned short* l) {
    __builtin_amdgcn_global_load_lds(
        (const __attribute__((address_space(1))) void*)(g),
        (__attribute__((address_space(3))) void*)(l), 16, 0, 0);
}

// ---------------------------------------------------------------------------
__global__ __launch_bounds__(256)
void cvt_kernel(const float* __restrict__ in, unsigned short* __restrict__ out) {
    long i = ((long)blockIdx.x * 256 + threadIdx.x) * 4;
    f32x4 v = *(const f32x4*)(in + i);
    u16x4 o;
    o.x = f2b(v.x); o.y = f2b(v.y); o.z = f2b(v.z); o.w = f2b(v.w);
    *(u16x4*)(out + i) = o;
}

// ---------------------------------------------------------------------------
__global__ __launch_bounds__(256)
void transW_kernel(const float* __restrict__ W0, const float* __restrict__ W1,
                   const float* __restrict__ W2, unsigned short* __restrict__ WT) {
    const float* W = (blockIdx.z == 0) ? W0 : (blockIdx.z == 1) ? W1 : W2;
    unsigned short* O = WT + (long)blockIdx.z * 1024 * 1024;
    __shared__ float t[32][33];
    int tid = threadIdx.x;
    int r  = tid >> 3;
    int c4 = tid & 7;
    int bi = blockIdx.x, bj = blockIdx.y;
    f32x4 v = *(const f32x4*)&W[(long)(bi * 32 + r) * 1024 + bj * 32 + c4 * 4];
    t[r][c4 * 4 + 0] = v.x; t[r][c4 * 4 + 1] = v.y;
    t[r][c4 * 4 + 2] = v.z; t[r][c4 * 4 + 3] = v.w;
    __syncthreads();
    u16x4 o;
    o.x = f2b(t[c4 * 4 + 0][r]); o.y = f2b(t[c4 * 4 + 1][r]);
    o.z = f2b(t[c4 * 4 + 2][r]); o.w = f2b(t[c4 * 4 + 3][r]);
    *(u16x4*)&O[(long)(bj * 32 + r) * 1024 + bi * 32 + c4 * 4] = o;
}

// ---------------------------------------------------------------------------
// Big-tile GEMM: C[m][n] = alpha * sum_k A[m][k] * Bt[n][k]
// 512 threads = 8 waves (2 M x 4 N). Per-wave output (BM/2) x 64.
// BK=64 per K-tile, double-buffered LDS, staged via global_load_lds w=16.
// T2 swizzle: LDS row r holds its 8 16B-granules permuted by g^(r&7);
// achieved by pre-swizzling the GLOBAL source column (linear LDS dest, rule 21)
// and XOR-ing the same term into the ds_read address.
// Pipeline: stage tile g+1 (front-loaded, async) -> ds_read+MFMA tile g
// -> one __syncthreads per tile (its vmcnt(0) lands on ~full-group-old loads).
// OMODE: 0 = bf16 out, 1 = f32 out.
// CSKIP: causal 128x256-block skip (scores): 2*bn > bm -> exit.
// CKLIM: causal K limit (PV, BM=128): kend = (bm+1)*BM.
template<int BM, int BN, int OMODE, bool CSKIP, bool CKLIM>
__global__ __launch_bounds__(512, 2)
void gemm_big(const unsigned short* __restrict__ A, int lda, long aStride,
              const unsigned short* __restrict__ Bt, int ldb, long bStride,
              void* __restrict__ Cv, int ldc, long cStride,
              int K, float alpha) {
    constexpr int MF = BM / 32;   // per-wave M fragments (BM/2 rows / 16)
    constexpr int NF = BN / 64;   // per-wave N fragments (64 cols / 16)
    constexpr int AI = BM / 64;   // stage instructions per thread for A tile
    constexpr int BI = BN / 64;
    const int bm = blockIdx.x, bn = blockIdx.y, bz = blockIdx.z;
    if (CSKIP && 2 * bn > bm) return;
    A  += (long)bz * aStride;
    Bt += (long)bz * bStride;

    const int tid  = threadIdx.x;
    const int lane = tid & 63;
    const int wid  = tid >> 6;          // 0..7
    const int wm   = wid >> 2;          // 0..1
    const int wn   = wid & 3;           // 0..3

    extern __shared__ __align__(16) unsigned short smem[];
    unsigned short* As = smem;                      // [2][BM*64]
    unsigned short* Bs = smem + 2 * BM * 64;        // [2][BN*64]

    f32x4 acc[MF][NF] = {};

    const int kend = CKLIM ? (bm + 1) * BM : K;
    const int nt   = kend / 64;

    // staging precompute: thread handles granule (i*512 + tid) of each tile
    const int srl  = tid >> 3;          // row within a 64-row stage slice
    const int sg   = (tid & 7) ^ (srl & 7);   // pre-swizzled source granule
    const int fr   = lane & 15;
    const int fg   = lane >> 4;
    const int rxor = (fr & 7) * 8;      // ds_read swizzle term (shorts)

    // ---- stage tile g: all loads issued back-to-back (async DMA) ----
    auto stage = [&](int g) {
        const int k0 = g * 64;
        unsigned short* da = As + (g & 1) * (BM * 64);
        #pragma unroll
        for (int i = 0; i < AI; ++i) {
            const int rl = i * 64 + srl;
            load_lds16(A + (long)(bm * BM + rl) * lda + k0 + sg * 8,
                       da + i * 4096 + wid * 512 + lane * 8);
        }
        unsigned short* db = Bs + (g & 1) * (BN * 64);
        #pragma unroll
        for (int i = 0; i < BI; ++i) {
            const int rl = i * 64 + srl;
            load_lds16(Bt + (long)(bn * BN + rl) * ldb + k0 + sg * 8,
                       db + i * 4096 + wid * 512 + lane * 8);
        }
    };

    stage(0);
    __syncthreads();

    for (int g = 0; g < nt; ++g) {
        if (g + 1 < nt) stage(g + 1);     // issue-early: hides under this tile's math
        const unsigned short* as = As + (g & 1) * (BM * 64);
        const unsigned short* bs = Bs + (g & 1) * (BN * 64);
        #pragma unroll
        for (int ks = 0; ks < 2; ++ks) {
            s16x8 af[MF], bf[NF];
            #pragma unroll
            for (int m = 0; m < MF; ++m) {
                const int row = wm * (BM / 2) + m * 16 + fr;
                af[m] = *(const s16x8*)&as[row * 64 + (((ks * 4 + fg) * 8) ^ rxor)];
            }
            #pragma unroll
            for (int n = 0; n < NF; ++n) {
                const int row = wn * 64 + n * 16 + fr;
                bf[n] = *(const s16x8*)&bs[row * 64 + (((ks * 4 + fg) * 8) ^ rxor)];
            }
            __builtin_amdgcn_s_setprio(1);
            #pragma unroll
            for (int m = 0; m < MF; ++m)
                #pragma unroll
                for (int n = 0; n < NF; ++n)
                    acc[m][n] = __builtin_amdgcn_mfma_f32_16x16x32_bf16(af[m], bf[n], acc[m][n], 0, 0, 0);
            __builtin_amdgcn_s_setprio(0);
        }
        __syncthreads();   // vmcnt(0)+lgkmcnt(0): tile g+1 ready; reads of g done
    }

    // epilogue: C/D layout col = lane&15, row = (lane>>4)*4 + reg
    const int crow0 = bm * BM + wm * (BM / 2);
    const int ccol0 = bn * BN + wn * 64;
    const int cr = (lane >> 4) * 4;
    const int cc = lane & 15;
    if (OMODE == 0) {
        unsigned short* C = (unsigned short*)Cv + (long)bz * cStride;
        #pragma unroll
        for (int m = 0; m < MF; ++m)
            #pragma unroll
            for (int r = 0; r < 4; ++r) {
                const long row = crow0 + m * 16 + cr + r;
                #pragma unroll
                for (int n = 0; n < NF; ++n)
                    C[row * ldc + ccol0 + n * 16 + cc] = f2b(acc[m][n][r] * alpha);
            }
    } else {
        float* C = (float*)Cv + (long)bz * cStride;
        #pragma unroll
        for (int m = 0; m < MF; ++m)
            #pragma unroll
            for (int r = 0; r < 4; ++r) {
                const long row = crow0 + m * 16 + cr + r;
                #pragma unroll
                for (int n = 0; n < NF; ++n)
                    C[row * ldc + ccol0 + n * 16 + cc] = acc[m][n][r] * alpha;
            }
    }
}

// ---------------------------------------------------------------------------
// Causal row softmax, in-place fp32 scores row -> bf16 P row (zero-filled past i).
__global__ __launch_bounds__(256)
void softmax_rows(float* __restrict__ scores) {
    const int i = blockIdx.x;
    const int z = blockIdx.y;
    float* row = scores + ((long)z * S_LEN + i) * S_LEN;
    const int c = i + 1;
    const int tid  = threadIdx.x;
    const int lane = tid & 63;
    const int wid  = tid >> 6;

    f32x4 v0 = ((const f32x4*)row)[tid];
    f32x4 v1 = ((const f32x4*)row)[tid + 256];
    const int j0 = tid * 4, j1 = (tid + 256) * 4;

    float m = -3.4e38f;
    #pragma unroll
    for (int e = 0; e < 4; e++) {
        if (j0 + e < c) m = fmaxf(m, v0[e]);
        if (j1 + e < c) m = fmaxf(m, v1[e]);
    }
    #pragma unroll
    for (int off = 32; off > 0; off >>= 1) m = fmaxf(m, __shfl_xor(m, off));
    __shared__ float redm[4];
    if (lane == 0) redm[wid] = m;
    __syncthreads();
    m = fmaxf(fmaxf(redm[0], redm[1]), fmaxf(redm[2], redm[3]));

    float e0[4], e1[4];
    float s = 0.f;
    #pragma unroll
    for (int e = 0; e < 4; e++) {
        e0[e] = (j0 + e < c) ? __expf(v0[e] - m) : 0.f;
        e1[e] = (j1 + e < c) ? __expf(v1[e] - m) : 0.f;
        s += e0[e] + e1[e];
    }
    #pragma unroll
    for (int off = 32; off > 0; off >>= 1) s += __shfl_xor(s, off);
    __shared__ float reds[4];
    if (lane == 0) reds[wid] = s;
    __syncthreads();   // loads retired before in-place writes
    s = reds[0] + reds[1] + reds[2] + reds[3];
    const float rinv = 1.f / s;

    unsigned short* P = (unsigned short*)row;
    u16x4 o0, o1;
    o0.x = f2b(e0[0] * rinv); o0.y = f2b(e0[1] * rinv);
    o0.z = f2b(e0[2] * rinv); o0.w = f2b(e0[3] * rinv);
    o1.x = f2b(e1[0] * rinv); o1.y = f2b(e1[1] * rinv);
    o1.z = f2b(e1[2] * rinv); o1.w = f2b(e1[3] * rinv);
    *(u16x4*)&P[j0] = o0;
    *(u16x4*)&P[j1] = o1;
}

// ---------------------------------------------------------------------------
extern "C" void kernel_launch(void* const* d_in, const int* in_sizes, int n_in,
                              void* d_out, int out_size, void* d_ws, size_t ws_size,
                              hipStream_t stream) {
    const float* x  = (const float*)d_in[0];
    const float* Wq = (const float*)d_in[1];
    const float* Wk = (const float*)d_in[2];
    const float* Wv = (const float*)d_in[3];
    float* out = (float*)d_out;
    char* ws = (char*)d_ws;
    const size_t MiB = 1ull << 20;

    unsigned short* xb  = (unsigned short*)(ws);              // [8192][1024] bf16
    unsigned short* WT  = (unsigned short*)(ws + 16 * MiB);   // 3x [1024][1024] bf16
    unsigned short* Qb  = (unsigned short*)(ws + 22 * MiB);   // [4][2048][1024]
    unsigned short* Kb  = (unsigned short*)(ws + 38 * MiB);   // [4][2048][1024]
    unsigned short* VbT = (unsigned short*)(ws + 54 * MiB);   // [1024][8192]
    float* scores       = (float*)(ws + 70 * MiB);            // nb x [2048][2048] fp32

    int nb;
    if      (ws_size >= (70 + 64) * MiB) nb = 4;
    else if (ws_size >= (70 + 32) * MiB) nb = 2;
    else                                 nb = 1;

    // opt-in to >64KB dynamic LDS (host-side, idempotent, capture-safe)
    const int LDS_QK = 2 * (256 + 256) * 64 * 2;   // 131072
    const int LDS_SM = 2 * (128 + 256) * 64 * 2;   // 98304
    hipFuncSetAttribute((const void*)gemm_big<256,256,0,false,false>,
                        hipFuncAttributeMaxDynamicSharedMemorySize, LDS_QK);
    hipFuncSetAttribute((const void*)gemm_big<128,256,0,false,false>,
                        hipFuncAttributeMaxDynamicSharedMemorySize, LDS_SM);
    hipFuncSetAttribute((const void*)gemm_big<128,256,1,true,false>,
                        hipFuncAttributeMaxDynamicSharedMemorySize, LDS_SM);
    hipFuncSetAttribute((const void*)gemm_big<128,256,1,false,true>,
                        hipFuncAttributeMaxDynamicSharedMemorySize, LDS_SM);

    // 1) converts
    cvt_kernel<<<8192, 256, 0, stream>>>(x, xb);
    transW_kernel<<<dim3(32, 32, 3), 256, 0, stream>>>(Wq, Wk, Wv, WT);

    // 2) projections
    // Q,K = x*W : 256x256 tiles, z picks {Wq->Qb, Wk->Kb} (Qb,Kb contiguous)
    gemm_big<256,256,0,false,false><<<dim3(32, 4, 2), 512, LDS_QK, stream>>>(
        xb, 1024, 0L, WT, 1024, (long)1024 * 1024,
        Qb, 1024, (long)8192 * 1024, 1024, 1.0f);
    // V^T = Wv^T * x^T : 128x256 tiles -> [1024][8192]
    gemm_big<128,256,0,false,false><<<dim3(8, 32, 1), 512, LDS_SM, stream>>>(
        WT + (long)2 * 1024 * 1024, 1024, 0L, xb, 1024, 0L,
        VbT, 8192, 0L, 1024, 1.0f);

    // 3) attention, chunked over batches
    const float alpha = 0.03125f;   // 1/sqrt(1024)
    for (int b0 = 0; b0 < NBATCH; b0 += nb) {
        const int nz = (NBATCH - b0 < nb) ? (NBATCH - b0) : nb;
        // scores = Q K^T * alpha  (causal 128x256-block skip)
        gemm_big<128,256,1,true,false><<<dim3(16, 8, nz), 512, LDS_SM, stream>>>(
            Qb + (long)b0 * S_LEN * D_DIM, 1024, (long)S_LEN * D_DIM,
            Kb + (long)b0 * S_LEN * D_DIM, 1024, (long)S_LEN * D_DIM,
            scores, S_LEN, (long)S_LEN * S_LEN, 1024, alpha);
        // softmax rows (in-place bf16 P, zero-filled past diagonal)
        softmax_rows<<<dim3(S_LEN, nz), 256, 0, stream>>>(scores);
        // O = P V  (K limited per 128-row block; P rows at bf16 stride 4096)
        gemm_big<128,256,1,false,true><<<dim3(16, 4, nz), 512, LDS_SM, stream>>>(
            (const unsigned short*)scores, 2 * S_LEN, 2L * S_LEN * S_LEN,
            VbT + (long)b0 * S_LEN, 8192, (long)S_LEN,
            out + (long)b0 * S_LEN * D_DIM, 1024, (long)S_LEN * D_DIM,
            S_LEN, 1.0f);
    }
}